// Round 1
// baseline (1077.826 us; speedup 1.0000x reference)
//
#include <hip/hip_runtime.h>

// Problem constants (from reference setup_inputs)
constexpr int B  = 2;
constexpr int T  = 2048;
constexpr int C  = 1024;
constexpr int H  = 16;
constexpr int HD = 64;
constexpr int BT = B * T;            // 4096 rows
constexpr int QKSZ = B * H * HD * T; // 4,194,304 floats per tensor

// ---------------------------------------------------------------------------
// GEMM: out = A @ W^T + bias.  A: 4096 x 1024 row-major, W: N x 1024 row-major.
// 128x128 block tile, BK=16, 256 threads, 8x8 register tile (split 64+64).
// MODE 0: fused QKV. A selected per column-block (query/key/value).
//         q,k written d-major [b,h,d,t]; v written t-major [b,h,t,d].
// MODE 1: plain row-major output (out-projection) -> d_out.
// ---------------------------------------------------------------------------
template <int MODE>
__global__ __launch_bounds__(256, 2) void gemm_k(
    const float* __restrict__ A0, const float* __restrict__ A1,
    const float* __restrict__ A2, const float* __restrict__ W,
    const float* __restrict__ bias, float* __restrict__ out)
{
    constexpr int K = 1024;
    __shared__ float Xs[16][132];
    __shared__ float Ws[16][132];

    const int tid = threadIdx.x;
    const int tn  = tid & 15;
    const int tm  = tid >> 4;
    const int bm  = blockIdx.x;   // row block (M/128 = 32)
    const int bn  = blockIdx.y;   // col block

    const int which = (MODE == 0) ? (bn >> 3) : 0;   // 1024/128 = 8 blocks per chunk
    const float* A = (MODE == 0) ? (which == 0 ? A0 : (which == 1 ? A1 : A2)) : A0;

    const int lf = tid & 3;    // k-float4 index (k = lf*4)
    const int lr = tid >> 2;   // row 0..63 within half-tile

    const float* Arow0 = A + (size_t)(bm * 128 + lr) * K;
    const float* Arow1 = Arow0 + (size_t)64 * K;
    const float* Wrow0 = W + (size_t)(bn * 128 + lr) * K;
    const float* Wrow1 = Wrow0 + (size_t)64 * K;

    // bias for this thread's 8 columns
    const float4 bi0 = *(const float4*)&bias[bn * 128 + tn * 4];
    const float4 bi1 = *(const float4*)&bias[bn * 128 + 64 + tn * 4];

    float acc[8][8];
#pragma unroll
    for (int i = 0; i < 8; ++i)
#pragma unroll
        for (int j = 0; j < 8; ++j) acc[i][j] = 0.0f;

    for (int k0 = 0; k0 < K; k0 += 16) {
        // issue global loads before the barrier (overlap with prior compute)
        const float4 xa = *(const float4*)(Arow0 + k0 + lf * 4);
        const float4 xb = *(const float4*)(Arow1 + k0 + lf * 4);
        const float4 wa = *(const float4*)(Wrow0 + k0 + lf * 4);
        const float4 wb = *(const float4*)(Wrow1 + k0 + lf * 4);
        __syncthreads();
        Xs[lf * 4 + 0][lr] = xa.x; Xs[lf * 4 + 1][lr] = xa.y;
        Xs[lf * 4 + 2][lr] = xa.z; Xs[lf * 4 + 3][lr] = xa.w;
        Xs[lf * 4 + 0][64 + lr] = xb.x; Xs[lf * 4 + 1][64 + lr] = xb.y;
        Xs[lf * 4 + 2][64 + lr] = xb.z; Xs[lf * 4 + 3][64 + lr] = xb.w;
        Ws[lf * 4 + 0][lr] = wa.x; Ws[lf * 4 + 1][lr] = wa.y;
        Ws[lf * 4 + 2][lr] = wa.z; Ws[lf * 4 + 3][lr] = wa.w;
        Ws[lf * 4 + 0][64 + lr] = wb.x; Ws[lf * 4 + 1][64 + lr] = wb.y;
        Ws[lf * 4 + 2][64 + lr] = wb.z; Ws[lf * 4 + 3][64 + lr] = wb.w;
        __syncthreads();

#pragma unroll
        for (int kk = 0; kk < 16; ++kk) {
            const float4 x0 = *(const float4*)&Xs[kk][tm * 4];
            const float4 x1 = *(const float4*)&Xs[kk][64 + tm * 4];
            const float4 w0 = *(const float4*)&Ws[kk][tn * 4];
            const float4 w1 = *(const float4*)&Ws[kk][64 + tn * 4];
            const float xr[8] = {x0.x, x0.y, x0.z, x0.w, x1.x, x1.y, x1.z, x1.w};
            const float wc[8] = {w0.x, w0.y, w0.z, w0.w, w1.x, w1.y, w1.z, w1.w};
#pragma unroll
            for (int i = 0; i < 8; ++i)
#pragma unroll
                for (int j = 0; j < 8; ++j) acc[i][j] += xr[i] * wc[j];
        }
    }

    const float bcol[8] = {bi0.x, bi0.y, bi0.z, bi0.w, bi1.x, bi1.y, bi1.z, bi1.w};

    if (MODE == 1) {
#pragma unroll
        for (int ih = 0; ih < 2; ++ih)
#pragma unroll
            for (int i = 0; i < 4; ++i) {
                const int m_e = bm * 128 + ih * 64 + tm * 4 + i;
#pragma unroll
                for (int jh = 0; jh < 2; ++jh) {
                    const int n0 = bn * 128 + jh * 64 + tn * 4;
                    float4 st;
                    st.x = acc[ih * 4 + i][jh * 4 + 0] + bcol[jh * 4 + 0];
                    st.y = acc[ih * 4 + i][jh * 4 + 1] + bcol[jh * 4 + 1];
                    st.z = acc[ih * 4 + i][jh * 4 + 2] + bcol[jh * 4 + 2];
                    st.w = acc[ih * 4 + i][jh * 4 + 3] + bcol[jh * 4 + 3];
                    *(float4*)&out[(size_t)m_e * C + n0] = st;
                }
            }
    } else {
#pragma unroll
        for (int ih = 0; ih < 2; ++ih)
#pragma unroll
            for (int i = 0; i < 4; ++i) {
                const int m_e = bm * 128 + ih * 64 + tm * 4 + i;
                const int b = m_e >> 11;        // /T
                const int t = m_e & (T - 1);
#pragma unroll
                for (int jh = 0; jh < 2; ++jh) {
                    const int n0  = bn * 128 + jh * 64 + tn * 4;
                    const int rem = n0 & (C - 1);
                    const int h   = rem >> 6;
                    const int d   = rem & (HD - 1);
                    const float v0 = acc[ih * 4 + i][jh * 4 + 0] + bcol[jh * 4 + 0];
                    const float v1 = acc[ih * 4 + i][jh * 4 + 1] + bcol[jh * 4 + 1];
                    const float v2 = acc[ih * 4 + i][jh * 4 + 2] + bcol[jh * 4 + 2];
                    const float v3 = acc[ih * 4 + i][jh * 4 + 3] + bcol[jh * 4 + 3];
                    if (which == 2) {
                        // V: [b,h,t,d] — contiguous in d
                        float4 st = {v0, v1, v2, v3};
                        *(float4*)&out[2 * (size_t)QKSZ +
                                       ((size_t)((b * H + h) * T + t)) * HD + d] = st;
                    } else {
                        // Q/K: d-major [b,h,d,t] so attention loads need no transpose
                        float* dst = out + (size_t)which * QKSZ +
                                     ((size_t)((b * H + h) * HD + d)) * T + t;
                        dst[0 * T] = v0; dst[1 * T] = v1; dst[2 * T] = v2; dst[3 * T] = v3;
                    }
                }
            }
    }
}

// ---------------------------------------------------------------------------
// Flash attention with the reference's additive band "mask":
// logits = (QK^T)*0.125 + (|tq-tk|<=win ? 1 : 0); softmax over ALL keys.
// Q,K are d-major [b,h,d,t]; V is [b,h,t,d]. BQ=64, Kt=64, 256 threads,
// 4x4 thread tiles. Output ctx written [b,t, h*64+d] for the out-proj GEMM.
// ---------------------------------------------------------------------------
__global__ __launch_bounds__(256, 2) void attn_k(
    const float* __restrict__ Qg, const float* __restrict__ Kg,
    const float* __restrict__ Vg, const int* __restrict__ wptr,
    float* __restrict__ ctx)
{
    __shared__ float Qs[64][64];
    __shared__ float Ks[64][64];
    __shared__ float Vs[64][64];
    __shared__ float Ps[64][68];   // [kj][qi], stride 68 keeps b128 writes clean

    const int tid = threadIdx.x;
    const int tn  = tid & 15;
    const int tm  = tid >> 4;
    const int qt  = blockIdx.x;    // 0..31
    const int bh  = blockIdx.y;    // 0..31
    const int b   = bh >> 4;
    const int h   = bh & 15;
    const int win = *wptr;

    // load Q tile: Qs[d][qi]
    {
        const int c4 = (tid & 15) * 4;
        const int r  = tid >> 4;
        const float* qbase = Qg + (size_t)bh * HD * T + (size_t)qt * 64;
#pragma unroll
        for (int p = 0; p < 4; ++p) {
            const int d = r + p * 16;
            *(float4*)&Qs[d][c4] = *(const float4*)&qbase[(size_t)d * T + c4];
        }
    }

    float m_i[4], l_i[4], o[4][4];
#pragma unroll
    for (int i = 0; i < 4; ++i) {
        m_i[i] = -1e30f; l_i[i] = 0.0f;
#pragma unroll
        for (int j = 0; j < 4; ++j) o[i][j] = 0.0f;
    }

    const float* kbase = Kg + (size_t)bh * HD * T;
    const float* vbase = Vg + (size_t)bh * T * HD;
    const int tq0 = qt * 64 + tm * 4;

    for (int kt = 0; kt < 32; ++kt) {
        __syncthreads();   // previous PV done before K/V overwrite
        {
            const int c4 = (tid & 15) * 4;
            const int r  = tid >> 4;
#pragma unroll
            for (int p = 0; p < 4; ++p) {
                const int rr = r + p * 16;
                *(float4*)&Ks[rr][c4] =
                    *(const float4*)&kbase[(size_t)rr * T + kt * 64 + c4];
                *(float4*)&Vs[rr][c4] =
                    *(const float4*)&vbase[(size_t)(kt * 64 + rr) * HD + c4];
            }
        }
        __syncthreads();

        // S = Q·K^T (outer-product over d)
        float s[4][4];
#pragma unroll
        for (int i = 0; i < 4; ++i)
#pragma unroll
            for (int j = 0; j < 4; ++j) s[i][j] = 0.0f;
#pragma unroll 8
        for (int d = 0; d < 64; ++d) {
            const float4 q4 = *(const float4*)&Qs[d][tm * 4];
            const float4 k4 = *(const float4*)&Ks[d][tn * 4];
            const float qr[4] = {q4.x, q4.y, q4.z, q4.w};
            const float kc[4] = {k4.x, k4.y, k4.z, k4.w};
#pragma unroll
            for (int i = 0; i < 4; ++i)
#pragma unroll
                for (int j = 0; j < 4; ++j) s[i][j] += qr[i] * kc[j];
        }

        // scale + additive band, online softmax
        const int tk0 = kt * 64 + tn * 4;
        float p[4][4];
#pragma unroll
        for (int i = 0; i < 4; ++i) {
            float rmax = -1e30f;
#pragma unroll
            for (int j = 0; j < 4; ++j) {
                int dist = (tq0 + i) - (tk0 + j);
                dist = dist < 0 ? -dist : dist;
                const float lg = s[i][j] * 0.125f + (dist <= win ? 1.0f : 0.0f);
                p[i][j] = lg;
                rmax = fmaxf(rmax, lg);
            }
#pragma unroll
            for (int msk = 1; msk < 16; msk <<= 1)
                rmax = fmaxf(rmax, __shfl_xor(rmax, msk, 64));
            const float mn    = fmaxf(m_i[i], rmax);
            const float alpha = __expf(m_i[i] - mn);
            float rs = 0.0f;
#pragma unroll
            for (int j = 0; j < 4; ++j) {
                p[i][j] = __expf(p[i][j] - mn);
                rs += p[i][j];
            }
#pragma unroll
            for (int msk = 1; msk < 16; msk <<= 1)
                rs += __shfl_xor(rs, msk, 64);
            l_i[i] = l_i[i] * alpha + rs;
            m_i[i] = mn;
#pragma unroll
            for (int j = 0; j < 4; ++j) o[i][j] *= alpha;
        }

        // P -> LDS transposed: Ps[kj][qi]
#pragma unroll
        for (int j = 0; j < 4; ++j) {
            const float4 pv = {p[0][j], p[1][j], p[2][j], p[3][j]};
            *(float4*)&Ps[tn * 4 + j][tm * 4] = pv;
        }
        __syncthreads();

        // O += P·V (outer-product over kj)
#pragma unroll 8
        for (int kj = 0; kj < 64; ++kj) {
            const float4 pp = *(const float4*)&Ps[kj][tm * 4];
            const float4 vv = *(const float4*)&Vs[kj][tn * 4];
            const float pr[4] = {pp.x, pp.y, pp.z, pp.w};
            const float vc[4] = {vv.x, vv.y, vv.z, vv.w};
#pragma unroll
            for (int i = 0; i < 4; ++i)
#pragma unroll
                for (int j = 0; j < 4; ++j) o[i][j] += pr[i] * vc[j];
        }
    }

    // normalize + store ctx[b, t, h*64 + d]
#pragma unroll
    for (int i = 0; i < 4; ++i) {
        const float inv = 1.0f / l_i[i];
        const int t = qt * 64 + tm * 4 + i;
        const float4 ov = {o[i][0] * inv, o[i][1] * inv, o[i][2] * inv, o[i][3] * inv};
        *(float4*)&ctx[((size_t)(b * T + t)) * C + h * HD + tn * 4] = ov;
    }
}

// ---------------------------------------------------------------------------
extern "C" void kernel_launch(void* const* d_in, const int* in_sizes, int n_in,
                              void* d_out, int out_size, void* d_ws, size_t ws_size,
                              hipStream_t stream)
{
    const float* query = (const float*)d_in[0];
    const float* key   = (const float*)d_in[1];
    const float* value = (const float*)d_in[2];
    const float* ipw   = (const float*)d_in[3];
    const float* ipb   = (const float*)d_in[4];
    const float* opw   = (const float*)d_in[5];
    const float* opb   = (const float*)d_in[6];
    const int*   win   = (const int*)d_in[7];

    float* ws  = (float*)d_ws;
    float* q   = ws;                 // [b,h,d,t]
    float* k   = ws + QKSZ;          // [b,h,d,t]
    float* v   = ws + 2 * (size_t)QKSZ; // [b,h,t,d]
    float* ctx = ws + 3 * (size_t)QKSZ; // [b*t, c]

    // fused QKV projection: N = 3072
    gemm_k<0><<<dim3(BT / 128, 3 * C / 128), 256, 0, stream>>>(
        query, key, value, ipw, ipb, ws);

    // flash attention with additive band
    attn_k<<<dim3(T / 64, B * H), 256, 0, stream>>>(q, k, v, win, ctx);

    // output projection: N = 1024
    gemm_k<1><<<dim3(BT / 128, C / 128), 256, 0, stream>>>(
        ctx, ctx, ctx, opw, opb, (float*)d_out);
}

// Round 2
// 276.574 us; speedup vs baseline: 3.8971x; 3.8971x over previous
//
#include <hip/hip_runtime.h>

typedef __attribute__((ext_vector_type(8)))  short short8;
typedef __attribute__((ext_vector_type(4)))  float f32x4;
typedef __attribute__((ext_vector_type(16))) float f32x16;

constexpr int B  = 2;
constexpr int T  = 2048;
constexpr int C  = 1024;
constexpr int H  = 16;
constexpr int HD = 64;

// ---------------- helpers ----------------
__device__ inline unsigned bf16rne(float a){
  unsigned u = __builtin_bit_cast(unsigned, a);
  u += 0x7fffu + ((u >> 16) & 1u);
  return u >> 16;
}
__device__ inline unsigned bf16pair(float a, float b){
  unsigned ua = __builtin_bit_cast(unsigned, a); ua += 0x7fffu + ((ua >> 16) & 1u);
  unsigned ub = __builtin_bit_cast(unsigned, b); ub += 0x7fffu + ((ub >> 16) & 1u);
  return (ua >> 16) | (ub & 0xffff0000u);
}
__device__ inline void gll16(const void* g, void* l){
  __builtin_amdgcn_global_load_lds(
      (const __attribute__((address_space(1))) unsigned*)g,
      (__attribute__((address_space(3))) unsigned*)l, 16, 0, 0);
}

// ---------------- weight fp32 -> bf16 convert ----------------
// dst covers Winbf (3072*1024) then Woutbf (1024*1024), contiguous.
__global__ void convert_k(const float* __restrict__ ipw, const float* __restrict__ opw,
                          unsigned* __restrict__ dst)
{
  const int i = blockIdx.x * 256 + threadIdx.x;   // 4 floats per thread
  const int e = i * 4;
  float4 v;
  if (e < 3145728) v = *(const float4*)(ipw + e);
  else             v = *(const float4*)(opw + (e - 3145728));
  dst[i*2+0] = bf16pair(v.x, v.y);
  dst[i*2+1] = bf16pair(v.z, v.w);
}

// ---------------- GEMM: out = A @ W^T + bias (m97-style MFMA) ----------------
// 128x128 tile, BK=32, 4 waves each 64x64 (4x4 of 16x16x32 bf16).
// MODE 0: QKV (A = fp32 query/key/value, converted during staging;
//          epilogue scatters bf16 into Q/K/V [b,h,t,d]).
// MODE 1: out-proj (A = bf16 ctx via global_load_lds; fp32 output + bias).
template<int MODE>
__global__ __launch_bounds__(256, 2) void gemm_k(
    const float* __restrict__ Aq, const float* __restrict__ Ak, const float* __restrict__ Av,
    const unsigned short* __restrict__ Abf,
    const unsigned short* __restrict__ Wb, const float* __restrict__ bias,
    unsigned short* __restrict__ Qb, unsigned short* __restrict__ Kb,
    unsigned short* __restrict__ Vb, float* __restrict__ outF)
{
  __shared__ __align__(16) unsigned short As[128*32];
  __shared__ __align__(16) unsigned short Bs[128*32];
  const int tid  = threadIdx.x, lane = tid & 63, wv = tid >> 6;
  const int wm   = wv & 1, wn = wv >> 1;
  const int bm   = blockIdx.x, bn = blockIdx.y;
  const int m16  = lane & 15, quad = lane >> 4;

  const int which = (MODE == 0) ? (bn >> 3) : 0;
  const float* A32 = (MODE == 0) ? (which == 0 ? Aq : (which == 1 ? Ak : Av)) : nullptr;

  f32x4 acc[4][4];
#pragma unroll
  for (int i = 0; i < 4; i++)
#pragma unroll
    for (int j = 0; j < 4; j++) acc[i][j] = (f32x4){0.f, 0.f, 0.f, 0.f};

  const int rowA = tid >> 1;                 // mode0 conv staging
  const int srow = wv * 32 + (lane >> 2);    // gll staging row (p adds 16)
  const int skp  = (lane & 3) * 8;

  for (int k0 = 0; k0 < 1024; k0 += 32) {
    __syncthreads();
    if constexpr (MODE == 0) {
      const float* ap = A32 + (size_t)(bm*128 + rowA)*1024 + k0 + (tid & 1)*16;
      const float4 a0 = *(const float4*)(ap);
      const float4 a1 = *(const float4*)(ap + 4);
      const float4 a2 = *(const float4*)(ap + 8);
      const float4 a3 = *(const float4*)(ap + 12);
      uint4 w0, w1;
      w0.x = bf16pair(a0.x,a0.y); w0.y = bf16pair(a0.z,a0.w);
      w0.z = bf16pair(a1.x,a1.y); w0.w = bf16pair(a1.z,a1.w);
      w1.x = bf16pair(a2.x,a2.y); w1.y = bf16pair(a2.z,a2.w);
      w1.z = bf16pair(a3.x,a3.y); w1.w = bf16pair(a3.z,a3.w);
      *(uint4*)((char*)As + rowA*64 + (tid & 1)*32)      = w0;
      *(uint4*)((char*)As + rowA*64 + (tid & 1)*32 + 16) = w1;
    } else {
#pragma unroll
      for (int p = 0; p < 2; p++)
        gll16(Abf + (size_t)(bm*128 + srow + p*16)*1024 + k0 + skp,
              (char*)As + wv*2048 + p*1024);
    }
#pragma unroll
    for (int p = 0; p < 2; p++)
      gll16(Wb + (size_t)(bn*128 + srow + p*16)*1024 + k0 + skp,
            (char*)Bs + wv*2048 + p*1024);
    __syncthreads();

    short8 af[4], bf[4];
#pragma unroll
    for (int i = 0; i < 4; i++)
      af[i] = *(const short8*)((const char*)As + (wm*64 + i*16 + m16)*64 + quad*16);
#pragma unroll
    for (int j = 0; j < 4; j++)
      bf[j] = *(const short8*)((const char*)Bs + (wn*64 + j*16 + m16)*64 + quad*16);
#pragma unroll
    for (int i = 0; i < 4; i++)
#pragma unroll
      for (int j = 0; j < 4; j++)
        acc[i][j] = __builtin_amdgcn_mfma_f32_16x16x32_bf16(af[i], bf[j], acc[i][j], 0,0,0);
  }

  // epilogue
#pragma unroll
  for (int j = 0; j < 4; j++) {
    const int n_e = bn*128 + wn*64 + j*16 + m16;
    const float bj = bias[n_e];
#pragma unroll
    for (int i = 0; i < 4; i++) {
      const int mbase = bm*128 + wm*64 + i*16 + quad*4;
#pragma unroll
      for (int r = 0; r < 4; r++) {
        const float v = acc[i][j][r] + bj;
        const int m_e = mbase + r;
        if constexpr (MODE == 1) {
          outF[(size_t)m_e * 1024 + n_e] = v;
        } else {
          const int b  = m_e >> 11, t = m_e & 2047;
          const int rem = n_e & 1023;
          const int hh = rem >> 6, dd = rem & 63;
          unsigned short* dst = (which == 0 ? Qb : (which == 1 ? Kb : Vb));
          dst[(size_t)((b*16 + hh)*2048 + t)*64 + dd] = (unsigned short)bf16rne(v);
        }
      }
    }
  }
}

// ---------------- V [b,h,t,d] -> Vt [b,h,d,t] ----------------
__global__ __launch_bounds__(256, 2) void transpose_v(
    const unsigned short* __restrict__ Vb, unsigned short* __restrict__ Vt)
{
  __shared__ __align__(16) unsigned short tile[64][72];
  const int tid = threadIdx.x, lane = tid & 63, wv = tid >> 6;
  const int bh = blockIdx.y, t0 = blockIdx.x * 64;
  const size_t base = (size_t)bh * T * HD;
#pragma unroll
  for (int p = 0; p < 2; p++) {
    const int dc = p*4 + wv;     // 0..7 d-chunk
    *(short8*)&tile[lane][dc*8] = *(const short8*)(Vb + base + (size_t)(t0 + lane)*64 + dc*8);
  }
  __syncthreads();
#pragma unroll
  for (int p = 0; p < 2; p++) {
    const int tcc = p*4 + wv;    // 0..7 t-chunk
    short8 v;
#pragma unroll
    for (int j = 0; j < 8; j++) v[j] = (short)tile[tcc*8 + j][lane];
    *(short8*)(Vt + base + (size_t)lane * T + t0 + tcc*8) = v;
  }
}

// ---------------- MFMA flash attention, S^T formulation ----------------
// S^T = K·Q^T (32x32x16), fixed-max softmax (logits bounded), P->A-frag via
// shfl_xor(32) fixup, O = P·V.  BQ=64 per block (2 q-halves x 2 kk-halves waves).
__global__ __launch_bounds__(256, 2) void attn_k(
    const unsigned short* __restrict__ Qb, const unsigned short* __restrict__ Kb,
    const unsigned short* __restrict__ Vt, const int* __restrict__ wptr,
    unsigned short* __restrict__ ctx)
{
  __shared__ __align__(16) char smem[16896];
  unsigned short* Kl = (unsigned short*)smem;           // 8 KB  [8 dchunk][64 kk][8]
  unsigned short* Vl = (unsigned short*)(smem + 8192);  // 8 KB  [8 kchunk][64 d][8]
  float* Om   = (float*)smem;                           // reuse after loop (16 KB)
  float* lbuf = (float*)(smem + 16384);                 // [2 wk][64]

  const int tid = threadIdx.x, lane = tid & 63, wv = tid >> 6;
  const int wq = wv >> 1, wk = wv & 1;
  const int h = lane >> 5, ln = lane & 31;
  const bool hs = (h == 1);
  const int qt = blockIdx.x, bh = blockIdx.y;
  const int win = *wptr;
  const int q0 = qt * 64 + wq * 32;
  const size_t hb = (size_t)bh * T * HD;

  short8 qf[4];
#pragma unroll
  for (int s = 0; s < 4; s++)
    qf[s] = *(const short8*)(Qb + hb + (size_t)(q0 + ln)*64 + s*16 + h*8);

  f32x16 O0, O1;
#pragma unroll
  for (int r = 0; r < 16; r++) { O0[r] = 0.f; O1[r] = 0.f; }
  float lpart = 0.f;
  const int tq = q0 + ln;

  for (int kt = 0; kt < 32; ++kt) {
    __syncthreads();
#pragma unroll
    for (int p = 0; p < 2; p++) {
      const int c2 = wv*2 + p;
      gll16(Kb + hb + (size_t)(kt*64 + lane)*64 + c2*8, (char*)Kl + c2*1024);
      gll16(Vt + hb + (size_t)lane*T + kt*64 + c2*8,    (char*)Vl + c2*1024);
    }
    __syncthreads();

    f32x16 st;
#pragma unroll
    for (int r = 0; r < 16; r++) st[r] = 0.f;
#pragma unroll
    for (int s = 0; s < 4; s++) {
      const short8 kf = *(const short8*)((const char*)Kl + (2*s + h)*1024 + (wk*32 + ln)*16);
      st = __builtin_amdgcn_mfma_f32_32x32x16_bf16(kf, qf[s], st, 0, 0, 0);
    }

    const int tkb = kt*64 + wk*32 + 4*h;
    float pr[16];
#pragma unroll
    for (int r = 0; r < 16; r++) {
      const int tk = tkb + (r & 3) + 8*(r >> 2);
      int d = tq - tk; d = d < 0 ? -d : d;
      const float v = st[r]*0.125f + (d <= win ? 1.0f : 0.0f);
      const float p = __expf(v);
      pr[r] = p; lpart += p;
    }
    unsigned pk[8];
#pragma unroll
    for (int g = 0; g < 8; g++) pk[g] = bf16pair(pr[2*g], pr[2*g+1]);

#pragma unroll
    for (int c = 0; c < 2; c++) {
      const unsigned ownA = hs ? pk[4*c+2] : pk[4*c+0];
      const unsigned ownB = hs ? pk[4*c+3] : pk[4*c+1];
      const unsigned sndA = hs ? pk[4*c+0] : pk[4*c+2];
      const unsigned sndB = hs ? pk[4*c+1] : pk[4*c+3];
      const unsigned rcvA = (unsigned)__shfl_xor((int)sndA, 32, 64);
      const unsigned rcvB = (unsigned)__shfl_xor((int)sndB, 32, 64);
      union { unsigned u[4]; short8 v; } P;
      P.u[0] = hs ? rcvA : ownA;
      P.u[1] = hs ? rcvB : ownB;
      P.u[2] = hs ? ownA : rcvA;
      P.u[3] = hs ? ownB : rcvB;
#pragma unroll
      for (int dt = 0; dt < 2; dt++) {
        const short8 vf = *(const short8*)((const char*)Vl + (wk*4 + 2*c + h)*1024 + (dt*32 + ln)*16);
        if (dt == 0) O0 = __builtin_amdgcn_mfma_f32_32x32x16_bf16(P.v, vf, O0, 0,0,0);
        else         O1 = __builtin_amdgcn_mfma_f32_32x32x16_bf16(P.v, vf, O1, 0,0,0);
      }
    }
  }

  const float lsum = lpart + __shfl_xor(lpart, 32, 64);
  __syncthreads();
  if (wk == 1) {
#pragma unroll
    for (int r = 0; r < 16; r++) {
      Om[wq*2048 + r*64 + lane]        = O0[r];
      Om[wq*2048 + (16 + r)*64 + lane] = O1[r];
    }
  }
  if (lane < 32) lbuf[wk*64 + wq*32 + lane] = lsum;
  __syncthreads();
  if (wk == 0) {
    const int b = bh >> 4, hh = bh & 15;
#pragma unroll
    for (int r = 0; r < 16; r++) {
      const int qrow = (r & 3) + 8*(r >> 2) + 4*h;
      const float lt = lbuf[wq*32 + qrow] + lbuf[64 + wq*32 + qrow];
      const float linv = 1.0f / lt;
      const int t = q0 + qrow;
      const float o0 = (O0[r] + Om[wq*2048 + r*64 + lane]) * linv;
      const float o1 = (O1[r] + Om[wq*2048 + (16 + r)*64 + lane]) * linv;
      unsigned short* cp = ctx + (size_t)(b*2048 + t)*1024 + hh*64;
      cp[ln]      = (unsigned short)bf16rne(o0);
      cp[32 + ln] = (unsigned short)bf16rne(o1);
    }
  }
}

// ---------------- launch ----------------
extern "C" void kernel_launch(void* const* d_in, const int* in_sizes, int n_in,
                              void* d_out, int out_size, void* d_ws, size_t ws_size,
                              hipStream_t stream)
{
  const float* query = (const float*)d_in[0];
  const float* key   = (const float*)d_in[1];
  const float* value = (const float*)d_in[2];
  const float* ipw   = (const float*)d_in[3];
  const float* ipb   = (const float*)d_in[4];
  const float* opw   = (const float*)d_in[5];
  const float* opb   = (const float*)d_in[6];
  const int*   win   = (const int*)d_in[7];

  char* ws = (char*)d_ws;
  unsigned short* Winbf  = (unsigned short*)(ws);             // 3072*1024
  unsigned short* Woutbf = (unsigned short*)(ws + 6291456);   // 1024*1024
  unsigned short* Qb     = (unsigned short*)(ws + 8388608);   // [b,h,t,d]
  unsigned short* Kb     = (unsigned short*)(ws + 16777216);  // [b,h,t,d]
  unsigned short* Vb     = (unsigned short*)(ws + 25165824);  // [b,h,t,d]
  unsigned short* Vt     = (unsigned short*)(ws + 33554432);  // [b,h,d,t]
  unsigned short* ctx    = (unsigned short*)(ws + 41943040);  // [4096][1024]

  convert_k<<<4096, 256, 0, stream>>>(ipw, opw, (unsigned*)Winbf);

  gemm_k<0><<<dim3(32, 24), 256, 0, stream>>>(
      query, key, value, nullptr, Winbf, ipb, Qb, Kb, Vb, nullptr);

  transpose_v<<<dim3(32, 32), 256, 0, stream>>>(Vb, Vt);

  attn_k<<<dim3(32, 32), 256, 0, stream>>>(Qb, Kb, Vt, win, ctx);

  gemm_k<1><<<dim3(32, 8), 256, 0, stream>>>(
      nullptr, nullptr, nullptr, ctx, Woutbf, opb, nullptr, nullptr, nullptr,
      (float*)d_out);
}

// Round 3
// 242.925 us; speedup vs baseline: 4.4369x; 1.1385x over previous
//
#include <hip/hip_runtime.h>

typedef __attribute__((ext_vector_type(8)))  short short8;
typedef __attribute__((ext_vector_type(4)))  short sh4;
typedef __attribute__((ext_vector_type(4)))  float f32x4;
typedef __attribute__((ext_vector_type(16))) float f32x16;

constexpr int B  = 2;
constexpr int T  = 2048;
constexpr int C  = 1024;
constexpr int H  = 16;
constexpr int HD = 64;

// ---------------- helpers ----------------
__device__ inline unsigned bf16rne(float a){
  unsigned u = __builtin_bit_cast(unsigned, a);
  u += 0x7fffu + ((u >> 16) & 1u);
  return u >> 16;
}
__device__ inline unsigned bf16pair(float a, float b){
  unsigned ua = __builtin_bit_cast(unsigned, a); ua += 0x7fffu + ((ua >> 16) & 1u);
  unsigned ub = __builtin_bit_cast(unsigned, b); ub += 0x7fffu + ((ub >> 16) & 1u);
  return (ua >> 16) | (ub & 0xffff0000u);
}
__device__ inline void gll16(const void* g, void* l){
  __builtin_amdgcn_global_load_lds(
      (const __attribute__((address_space(1))) unsigned*)g,
      (__attribute__((address_space(3))) unsigned*)l, 16, 0, 0);
}
__device__ inline float exp2f_(float x){
#if __has_builtin(__builtin_amdgcn_exp2f)
  return __builtin_amdgcn_exp2f(x);
#else
  return __builtin_exp2f(x);
#endif
}

// ---------------- fp32 -> bf16 convert: weights + qkv inputs ----------------
// dst regions (floats): ipw 3145728 | opw 1048576 | q 4194304 | k | v
__global__ void convert_k(const float* __restrict__ ipw, const float* __restrict__ opw,
                          const float* __restrict__ q, const float* __restrict__ k,
                          const float* __restrict__ v, unsigned* __restrict__ dst)
{
  const int i = blockIdx.x * 256 + threadIdx.x;   // 4 floats per thread
  const long e = (long)i * 4;
  const float* src; long off;
  if      (e <  3145728) { src = ipw; off = e; }
  else if (e <  4194304) { src = opw; off = e - 3145728; }
  else if (e <  8388608) { src = q;   off = e - 4194304; }
  else if (e < 12582912) { src = k;   off = e - 8388608; }
  else                   { src = v;   off = e - 12582912; }
  const float4 x = *(const float4*)(src + off);
  dst[i*2+0] = bf16pair(x.x, x.y);
  dst[i*2+1] = bf16pair(x.z, x.w);
}

// ---------------- GEMM: out = A @ W^T + bias (m97-style MFMA) ----------------
// 128x128 tile, BK=32, 4 waves each 64x64 (4x4 of 16x16x32 bf16), all-gll staging.
// MODE 0: QKV. A in {Qin,Kin,Vin} (bf16). Epilogue: Q,K -> [b,h,t,d] scalar;
//          V -> Vt [b,h,d,t] packed 8B stores.
// MODE 1: out-proj (A = ctx bf16; fp32 row-major output + bias).
template<int MODE>
__global__ __launch_bounds__(256, 2) void gemm_k(
    const unsigned short* __restrict__ A0, const unsigned short* __restrict__ A1,
    const unsigned short* __restrict__ A2,
    const unsigned short* __restrict__ Wb, const float* __restrict__ bias,
    unsigned short* __restrict__ Qb, unsigned short* __restrict__ Kb,
    unsigned short* __restrict__ Vt, float* __restrict__ outF)
{
  __shared__ __align__(16) unsigned short As[128*32];
  __shared__ __align__(16) unsigned short Bs[128*32];
  const int tid  = threadIdx.x, lane = tid & 63, wv = tid >> 6;
  const int wm   = wv & 1, wn = wv >> 1;
  const int bm   = blockIdx.x, bn = blockIdx.y;
  const int m16  = lane & 15, quad = lane >> 4;

  const int which = (MODE == 0) ? (bn >> 3) : 0;
  const unsigned short* A = (which == 0) ? A0 : (which == 1 ? A1 : A2);

  f32x4 acc[4][4];
#pragma unroll
  for (int i = 0; i < 4; i++)
#pragma unroll
    for (int j = 0; j < 4; j++) acc[i][j] = (f32x4){0.f, 0.f, 0.f, 0.f};

  const int srow = wv * 32 + (lane >> 2);    // staging row (p adds 16)
  const int skp  = (lane & 3) * 8;

  for (int k0 = 0; k0 < 1024; k0 += 32) {
    __syncthreads();
#pragma unroll
    for (int p = 0; p < 2; p++) {
      gll16(A  + (size_t)(bm*128 + srow + p*16)*1024 + k0 + skp,
            (char*)As + wv*2048 + p*1024);
      gll16(Wb + (size_t)(bn*128 + srow + p*16)*1024 + k0 + skp,
            (char*)Bs + wv*2048 + p*1024);
    }
    __syncthreads();

    short8 af[4], bf[4];
#pragma unroll
    for (int i = 0; i < 4; i++)
      af[i] = *(const short8*)((const char*)As + (wm*64 + i*16 + m16)*64 + quad*16);
#pragma unroll
    for (int j = 0; j < 4; j++)
      bf[j] = *(const short8*)((const char*)Bs + (wn*64 + j*16 + m16)*64 + quad*16);
#pragma unroll
    for (int i = 0; i < 4; i++)
#pragma unroll
      for (int j = 0; j < 4; j++)
        acc[i][j] = __builtin_amdgcn_mfma_f32_16x16x32_bf16(af[i], bf[j], acc[i][j], 0,0,0);
  }

  // epilogue
#pragma unroll
  for (int j = 0; j < 4; j++) {
    const int n_e = bn*128 + wn*64 + j*16 + m16;
    const float bj = bias[n_e];
    const int rem = n_e & 1023;
    const int hh = rem >> 6, dd = rem & 63;
#pragma unroll
    for (int i = 0; i < 4; i++) {
      const int mbase = bm*128 + wm*64 + i*16 + quad*4;
      if constexpr (MODE == 1) {
#pragma unroll
        for (int r = 0; r < 4; r++)
          outF[(size_t)(mbase + r) * 1024 + n_e] = acc[i][j][r] + bj;
      } else {
        const int b = mbase >> 11, tl = mbase & 2047;
        if (which == 2) {
          sh4 pv;
#pragma unroll
          for (int r = 0; r < 4; r++) pv[r] = (short)bf16rne(acc[i][j][r] + bj);
          *(sh4*)(Vt + ((size_t)((b*16 + hh)*64 + dd))*2048 + tl) = pv;
        } else {
          unsigned short* dst = (which == 0 ? Qb : Kb);
#pragma unroll
          for (int r = 0; r < 4; r++)
            dst[(size_t)((b*16 + hh)*2048 + tl + r)*64 + dd] =
                (unsigned short)bf16rne(acc[i][j][r] + bj);
        }
      }
    }
  }
}

// ---------------- MFMA flash attention, S^T formulation ----------------
// S^T = K·Q^T (32x32x16); exp2-domain softmax with wave-uniform band hoisting;
// l via MFMA-with-ones; P packed by v_perm (truncate) + shfl fixup; O = P·V.
__global__ __launch_bounds__(256, 2) void attn_k(
    const unsigned short* __restrict__ Qb, const unsigned short* __restrict__ Kb,
    const unsigned short* __restrict__ Vt, const int* __restrict__ wptr,
    unsigned short* __restrict__ ctx)
{
  __shared__ __align__(16) char smem[16896];
  unsigned short* Kl = (unsigned short*)smem;           // 8 KB  [8 dchunk][64 kk][8]
  unsigned short* Vl = (unsigned short*)(smem + 8192);  // 8 KB  [8 tchunk][64 d][8]
  float* Om   = (float*)smem;                           // reuse after loop (16 KB)
  float* lbuf = (float*)(smem + 16384);                 // [2 wq][32]

  const int tid = threadIdx.x, lane = tid & 63, wv = tid >> 6;
  const int wq = wv >> 1, wk = wv & 1;
  const int h = lane >> 5, ln = lane & 31;
  const bool hs = (h == 1);
  const int qt = blockIdx.x, bh = blockIdx.y;
  const int win = *wptr;
  const int q0 = qt * 64 + wq * 32;
  const size_t hb = (size_t)bh * T * HD;

  constexpr float LOG2E = 1.44269504f;
  constexpr float C1    = 0.125f * LOG2E;

  short8 qf[4];
#pragma unroll
  for (int s = 0; s < 4; s++)
    qf[s] = *(const short8*)(Qb + hb + (size_t)(q0 + ln)*64 + s*16 + h*8);

  short8 onesv;
#pragma unroll
  for (int jj = 0; jj < 8; jj++) onesv[jj] = (short)0x3F80;

  f32x16 O0, O1, Lacc, Zv;
#pragma unroll
  for (int r = 0; r < 16; r++) { O0[r] = 0.f; O1[r] = 0.f; Lacc[r] = 0.f; Zv[r] = 0.f; }
  const int tq = q0 + ln;

  for (int kt = 0; kt < 32; ++kt) {
    __syncthreads();
#pragma unroll
    for (int p = 0; p < 2; p++) {
      const int c2 = wv*2 + p;
      gll16(Kb + hb + (size_t)(kt*64 + lane)*64 + c2*8, (char*)Kl + c2*1024);
      gll16(Vt + hb + (size_t)lane*T + kt*64 + c2*8,    (char*)Vl + c2*1024);
    }
    __syncthreads();

    // S^T = K·Q^T
    f32x16 st;
#pragma unroll
    for (int s = 0; s < 4; s++) {
      const short8 kf = *(const short8*)((const char*)Kl + (2*s + h)*1024 + (wk*32 + ln)*16);
      st = __builtin_amdgcn_mfma_f32_32x32x16_bf16(kf, qf[s], (s == 0 ? Zv : st), 0, 0, 0);
    }

    // softmax numerator, exp2 domain, band hoisted when wave-uniform
    const int kb = kt*64 + wk*32;
    int sep = 0;
    if (kb > q0 + 31) sep = kb - (q0 + 31);
    else if (q0 > kb + 31) sep = q0 - (kb + 31);
    const int d1 = kb + 31 - q0, d2 = q0 + 31 - kb;
    const int dmax = max(d1 < 0 ? -d1 : d1, d2 < 0 ? -d2 : d2);

    float pr[16];
    if (sep > win) {
#pragma unroll
      for (int r = 0; r < 16; r++) pr[r] = exp2f_(st[r] * C1);
    } else if (dmax <= win) {
#pragma unroll
      for (int r = 0; r < 16; r++) pr[r] = exp2f_(__builtin_fmaf(st[r], C1, LOG2E));
    } else {
      const int tkb = kb + 4*h;
#pragma unroll
      for (int r = 0; r < 16; r++) {
        const int tk = tkb + (r & 3) + 8*(r >> 2);
        int dd = tq - tk; dd = dd < 0 ? -dd : dd;
        pr[r] = exp2f_(__builtin_fmaf(st[r], C1, dd <= win ? LOG2E : 0.0f));
      }
    }

    // pack pairs (truncate; bias cancels against MFMA-computed l)
    unsigned pk[8];
#pragma unroll
    for (int g = 0; g < 8; g++)
      pk[g] = __builtin_amdgcn_perm(__builtin_bit_cast(unsigned, pr[2*g+1]),
                                    __builtin_bit_cast(unsigned, pr[2*g]),
                                    0x07060302u);

#pragma unroll
    for (int c = 0; c < 2; c++) {
      const unsigned sh0 = (unsigned)__shfl_xor((int)pk[4*c+0], 32, 64);
      const unsigned sh1 = (unsigned)__shfl_xor((int)pk[4*c+1], 32, 64);
      const unsigned sh2 = (unsigned)__shfl_xor((int)pk[4*c+2], 32, 64);
      const unsigned sh3 = (unsigned)__shfl_xor((int)pk[4*c+3], 32, 64);
      union { unsigned u[4]; short8 v; } P;
      P.u[0] = hs ? sh2 : pk[4*c+0];
      P.u[1] = hs ? sh3 : pk[4*c+1];
      P.u[2] = hs ? pk[4*c+2] : sh0;
      P.u[3] = hs ? pk[4*c+3] : sh1;
#pragma unroll
      for (int dt = 0; dt < 2; dt++) {
        const short8 vf = *(const short8*)((const char*)Vl + (wk*4 + 2*c + h)*1024 + (dt*32 + ln)*16);
        if (dt == 0) O0 = __builtin_amdgcn_mfma_f32_32x32x16_bf16(P.v, vf, O0, 0,0,0);
        else         O1 = __builtin_amdgcn_mfma_f32_32x32x16_bf16(P.v, vf, O1, 0,0,0);
      }
      Lacc = __builtin_amdgcn_mfma_f32_32x32x16_bf16(P.v, onesv, Lacc, 0,0,0);
    }
  }

  __syncthreads();
  if (wk == 1) {
#pragma unroll
    for (int r = 0; r < 16; r++) {
      Om[wq*2048 + r*64 + lane]        = O0[r];
      Om[wq*2048 + (16 + r)*64 + lane] = O1[r];
    }
    if (ln == 0) {
#pragma unroll
      for (int r = 0; r < 16; r++)
        lbuf[wq*32 + (r & 3) + 8*(r >> 2) + 4*h] = Lacc[r];
    }
  }
  __syncthreads();
  if (wk == 0) {
    const int b = bh >> 4, hh = bh & 15;
#pragma unroll
    for (int r = 0; r < 16; r++) {
      const int qrow = (r & 3) + 8*(r >> 2) + 4*h;
      const float lt = Lacc[r] + lbuf[wq*32 + qrow];
      const float linv = 1.0f / lt;
      const int t = q0 + qrow;
      const float o0 = (O0[r] + Om[wq*2048 + r*64 + lane]) * linv;
      const float o1 = (O1[r] + Om[wq*2048 + (16 + r)*64 + lane]) * linv;
      unsigned short* cp = ctx + (size_t)(b*2048 + t)*1024 + hh*64;
      cp[ln]      = (unsigned short)bf16rne(o0);
      cp[32 + ln] = (unsigned short)bf16rne(o1);
    }
  }
}

// ---------------- launch ----------------
extern "C" void kernel_launch(void* const* d_in, const int* in_sizes, int n_in,
                              void* d_out, int out_size, void* d_ws, size_t ws_size,
                              hipStream_t stream)
{
  const float* query = (const float*)d_in[0];
  const float* key   = (const float*)d_in[1];
  const float* value = (const float*)d_in[2];
  const float* ipw   = (const float*)d_in[3];
  const float* ipb   = (const float*)d_in[4];
  const float* opw   = (const float*)d_in[5];
  const float* opb   = (const float*)d_in[6];
  const int*   win   = (const int*)d_in[7];

  char* ws = (char*)d_ws;
  unsigned short* Winbf  = (unsigned short*)(ws);             // 3072*1024
  unsigned short* Woutbf = (unsigned short*)(ws + 6291456);   // 1024*1024
  unsigned short* Qin    = (unsigned short*)(ws + 8388608);   // [4096,1024] bf16
  unsigned short* Kin    = (unsigned short*)(ws + 16777216);
  unsigned short* Vin    = (unsigned short*)(ws + 25165824);
  unsigned short* Qb     = (unsigned short*)(ws + 33554432);  // [b,h,t,d]
  unsigned short* Kb     = (unsigned short*)(ws + 41943040);  // [b,h,t,d]
  unsigned short* Vt     = (unsigned short*)(ws + 50331648);  // [b,h,d,t]
  unsigned short* ctx    = (unsigned short*)(ws + 58720256);  // [4096][1024]

  convert_k<<<16384, 256, 0, stream>>>(ipw, opw, query, key, value, (unsigned*)ws);

  gemm_k<0><<<dim3(32, 24), 256, 0, stream>>>(
      Qin, Kin, Vin, Winbf, ipb, Qb, Kb, Vt, nullptr);

  attn_k<<<dim3(32, 32), 256, 0, stream>>>(Qb, Kb, Vt, win, ctx);

  gemm_k<1><<<dim3(32, 8), 256, 0, stream>>>(
      ctx, ctx, ctx, Woutbf, opb, nullptr, nullptr, nullptr, (float*)d_out);
}